// Round 4
// baseline (6528.180 us; speedup 1.0000x reference)
//
#include <hip/hip_runtime.h>
#include <math.h>

// KMeansGrouping: B=32, N=4096, D=256, K=24, 25 iters.
// Round 4: round-1/2's bit-identical f64 trajectory (inv_norm, psums, center
// updates, counts) + round-3's high-occupancy assignment structure, with the
// assignment dots ALSO in f64 (reassociation-only ~1e-16 perturbation vs the
// verified trajectory; f32-in-the-feedback-loop was round 3's failure).
// Deterministic fixed-order reductions everywhere (graph replay identical).

#define BATCH 32
#define NPTS 4096
#define DIM 256
#define NSLOT 24
#define NITER 25
#define NCHUNK 16
#define PTS 256 // points per k_sum block (matches round-2 phase-2 order)

// ---------------- K0: per-point inverse norm (f64) ----------------
__global__ __launch_bounds__(256) void k_norm(const float* __restrict__ feat,
                                              double* __restrict__ inv_norm) {
  int lane = threadIdx.x & 63;
  int wid = threadIdx.x >> 6;
  int p = blockIdx.x * 4 + wid; // one wave per point
  const float4 v = *(const float4*)(feat + (size_t)p * DIM + lane * 4);
  double s = (double)v.x * v.x + (double)v.y * v.y + (double)v.z * v.z + (double)v.w * v.w;
#pragma unroll
  for (int m = 32; m; m >>= 1) s += __shfl_xor(s, m);
  if (lane == 0) inv_norm[p] = 1.0 / fmax(sqrt(s), 1e-12);
}

__device__ __forceinline__ double block_sum_256(double v, double* red) {
#pragma unroll
  for (int m = 32; m; m >>= 1) v += __shfl_xor(v, m);
  int w = threadIdx.x >> 6;
  if ((threadIdx.x & 63) == 0) red[w] = v;
  __syncthreads();
  return red[0] + red[1] + red[2] + red[3];
}

// ---------------- K0b: initial centers (f64 row-major + f64 [d][k]) -------
// init_idx = floor(linspace(0, N-1, K)): idx_k = floor(k*4095/23).
__global__ __launch_bounds__(256) void k_init_centers(const float* __restrict__ feat,
                                                      const double* __restrict__ inv_norm,
                                                      double* __restrict__ centers,
                                                      double* __restrict__ cT64,
                                                      double* __restrict__ c_sq) {
  __shared__ double red[4];
  int t = threadIdx.x, k = blockIdx.x, b = blockIdx.y;
  int idx = (int)((double)k * (NPTS - 1) / (NSLOT - 1));
  double v = (double)feat[((size_t)b * NPTS + idx) * DIM + t] * inv_norm[b * NPTS + idx];
  centers[((size_t)b * NSLOT + k) * DIM + t] = v;
  cT64[((size_t)b * DIM + t) * NSLOT + k] = v;
  double s = block_sum_256(v * v, red);
  if (t == 0) c_sq[b * NSLOT + k] = s;
}

// ---------------- K0c: tiled transpose feat -> xT[b][d][n] (f32) ----------
__global__ __launch_bounds__(256) void k_transpose(const float* __restrict__ feat,
                                                   float* __restrict__ xT) {
  __shared__ float tile[64][65];
  int ix = threadIdx.x & 63, iy = threadIdx.x >> 6;
  int bx = blockIdx.x, by = blockIdx.y, b = blockIdx.z;
  const float* fb = feat + ((size_t)b * NPTS + bx * 64) * DIM + by * 64;
#pragma unroll
  for (int r = 0; r < 64; r += 4)
    tile[r + iy][ix] = fb[(size_t)(r + iy) * DIM + ix];
  __syncthreads();
  float* xb = xT + ((size_t)b * DIM + by * 64) * NPTS + bx * 64;
#pragma unroll
  for (int r = 0; r < 64; r += 4)
    xb[(size_t)(r + iy) * NPTS + ix] = tile[ix][r + iy];
}

// ---------------- K1: assignment (f64), quarter-D per wave ----------------
// Block: 64 points x 4 waves; wave q handles dims [64q, 64q+64). Centers in
// cT64[b][d][k] read wave-uniform -> scalar loads. Waves 1..3 deposit f64
// partial dots in LDS; wave 0 combines in fixed order, scores, argmins
// (strict < = first occurrence), writes assign.
template <bool USE_T>
__global__ __launch_bounds__(256) void k_assign(const float* __restrict__ feat,
                                                const float* __restrict__ xT,
                                                const double* __restrict__ inv_norm,
                                                const double* __restrict__ cT64,
                                                const double* __restrict__ c_sq,
                                                int* __restrict__ assign) {
  __shared__ double part[3][64][NSLOT]; // 36864 B
  int lane = threadIdx.x & 63;
  int q = __builtin_amdgcn_readfirstlane(threadIdx.x >> 6);
  int blk = blockIdx.x, b = blockIdx.y;
  int n = blk * 64 + lane;
  const double* cb = cT64 + ((size_t)b * DIM + q * 64) * NSLOT;

  double dot[NSLOT];
#pragma unroll
  for (int k = 0; k < NSLOT; ++k) dot[k] = 0.0;

  for (int d = 0; d < 64; d += 4) {
    double x0, x1, x2, x3;
    if (USE_T) {
      const float* xp = xT + ((size_t)b * DIM + q * 64 + d) * NPTS + n;
      x0 = (double)xp[0];
      x1 = (double)xp[NPTS];
      x2 = (double)xp[2 * NPTS];
      x3 = (double)xp[3 * NPTS];
    } else {
      float4 v = *(const float4*)(feat + ((size_t)b * NPTS + n) * DIM + q * 64 + d);
      x0 = (double)v.x; x1 = (double)v.y; x2 = (double)v.z; x3 = (double)v.w;
    }
    const double* cp = cb + (size_t)d * NSLOT; // wave-uniform -> s_load
#pragma unroll
    for (int k = 0; k < NSLOT; ++k) {
      double s = dot[k];
      s = fma(x0, cp[k], s);
      s = fma(x1, cp[NSLOT + k], s);
      s = fma(x2, cp[2 * NSLOT + k], s);
      s = fma(x3, cp[3 * NSLOT + k], s);
      dot[k] = s;
    }
  }

  if (q) {
#pragma unroll
    for (int k = 0; k < NSLOT; ++k) part[q - 1][lane][k] = dot[k];
  }
  __syncthreads();

  if (q == 0) {
    double inv = inv_norm[b * NPTS + n];
    const double* csq = c_sq + b * NSLOT; // uniform -> s_load
    int a = 0;
    double best = 0.0;
#pragma unroll
    for (int k = 0; k < NSLOT; ++k) {
      double df = dot[k] + part[0][lane][k] + part[1][lane][k] + part[2][lane][k];
      double s = csq[k] - 2.0 * (df * inv);
      if (k == 0) { best = s; }
      else if (s < best) { best = s; a = k; }
    }
    assign[b * NPTS + n] = a;
  }
}

// ---------------- K2: partial center sums (f64, round-2 order) ----------
#define CASE_ACC(i) \
  case i: acc[i] += xv; ++cnt[i]; break;

__global__ __launch_bounds__(256) void k_sum(const float* __restrict__ feat,
                                             const double* __restrict__ inv_norm,
                                             const int* __restrict__ assign,
                                             double* __restrict__ psums,
                                             int* __restrict__ pcnts) {
  int t = threadIdx.x, ch = blockIdx.x, b = blockIdx.y;
  double acc[NSLOT];
  int cnt[NSLOT];
#pragma unroll
  for (int k = 0; k < NSLOT; ++k) { acc[k] = 0.0; cnt[k] = 0; }

  const float* fb = feat + ((size_t)b * NPTS + ch * PTS) * DIM + t;
  const double* ib = inv_norm + b * NPTS + ch * PTS;
  const int* ab = assign + b * NPTS + ch * PTS;
  for (int p = 0; p < PTS; ++p) {
    int a_s = __builtin_amdgcn_readfirstlane(ab[p]); // block-uniform
    double xv = (double)fb[(size_t)p * DIM] * ib[p];
    switch (a_s) {
      CASE_ACC(0) CASE_ACC(1) CASE_ACC(2) CASE_ACC(3)
      CASE_ACC(4) CASE_ACC(5) CASE_ACC(6) CASE_ACC(7)
      CASE_ACC(8) CASE_ACC(9) CASE_ACC(10) CASE_ACC(11)
      CASE_ACC(12) CASE_ACC(13) CASE_ACC(14) CASE_ACC(15)
      CASE_ACC(16) CASE_ACC(17) CASE_ACC(18) CASE_ACC(19)
      CASE_ACC(20) CASE_ACC(21) CASE_ACC(22) CASE_ACC(23)
    }
  }

  double* ps = psums + ((size_t)(b * NCHUNK + ch) * NSLOT) * DIM + t;
#pragma unroll
  for (int k = 0; k < NSLOT; ++k) ps[(size_t)k * DIM] = acc[k];
  if (t == 0) {
    int* pc = pcnts + (b * NCHUNK + ch) * NSLOT;
#pragma unroll
    for (int k = 0; k < NSLOT; ++k) pc[k] = cnt[k];
  }
}

// ---------------- K3: reduce partials -> new centers + cT64 + c_sq --------
__global__ __launch_bounds__(256) void k_update(const double* __restrict__ psums,
                                                const int* __restrict__ pcnts,
                                                double* __restrict__ centers,
                                                double* __restrict__ cT64,
                                                double* __restrict__ c_sq) {
  __shared__ double red[4];
  int t = threadIdx.x, k = blockIdx.x, b = blockIdx.y;
  double s = 0.0; // fixed order over chunks (identical to round 2)
#pragma unroll
  for (int ch = 0; ch < NCHUNK; ++ch)
    s += psums[((size_t)(b * NCHUNK + ch) * NSLOT + k) * DIM + t];
  int cnt = 0;
#pragma unroll
  for (int ch = 0; ch < NCHUNK; ++ch)
    cnt += pcnts[(b * NCHUNK + ch) * NSLOT + k];
  size_t ci = ((size_t)b * NSLOT + k) * DIM + t;
  double nc = (cnt > 0) ? (s / (double)cnt) : centers[ci];
  centers[ci] = nc;
  cT64[((size_t)b * DIM + t) * NSLOT + k] = nc;
  double sq = block_sum_256(nc * nc, red);
  if (t == 0) c_sq[b * NSLOT + k] = sq;
}

// ---------------- K4: masks + centers output ----------------
__global__ __launch_bounds__(256) void k_mask(const int* __restrict__ assign,
                                              float* __restrict__ masks) {
  int t = threadIdx.x, nc = blockIdx.x, k = blockIdx.y, b = blockIdx.z;
  int n = nc * 256 + t;
  masks[((size_t)b * NSLOT + k) * NPTS + n] = (assign[b * NPTS + n] == k) ? 1.0f : 0.0f;
}

__global__ __launch_bounds__(256) void k_copyc(const double* __restrict__ centers,
                                               float* __restrict__ out_centers) {
  int t = threadIdx.x, k = blockIdx.x, b = blockIdx.y;
  size_t i = ((size_t)b * NSLOT + k) * DIM + t;
  out_centers[i] = (float)centers[i];
}

extern "C" void kernel_launch(void* const* d_in, const int* in_sizes, int n_in,
                              void* d_out, int out_size, void* d_ws, size_t ws_size,
                              hipStream_t stream) {
  (void)in_sizes; (void)n_in; (void)out_size;
  const float* feat = (const float*)d_in[0];
  float* out_centers = (float*)d_out;                           // (32,24,256)
  float* out_masks = out_centers + (size_t)BATCH * NSLOT * DIM; // (32,24,4096)

  // workspace layout: ~30 MB fixed + optional 134 MB xT at the tail.
  char* ws = (char*)d_ws;
  double* inv_norm = (double*)ws; ws += (size_t)BATCH * NPTS * 8;                 // 1.0 MB
  double* centers  = (double*)ws; ws += (size_t)BATCH * NSLOT * DIM * 8;          // 1.5 MB
  double* cT64     = (double*)ws; ws += (size_t)BATCH * DIM * NSLOT * 8;          // 1.5 MB
  double* c_sq     = (double*)ws; ws += (size_t)BATCH * NSLOT * 8;                // 6 KB
  int* assign      = (int*)ws;    ws += (size_t)BATCH * NPTS * 4;                 // 0.5 MB
  double* psums    = (double*)ws; ws += (size_t)BATCH * NCHUNK * NSLOT * DIM * 8; // 25 MB
  int* pcnts       = (int*)ws;    ws += (size_t)BATCH * NCHUNK * NSLOT * 4;       // 48 KB
  float* xT        = (float*)ws;
  size_t need_xT = (size_t)(ws - (char*)d_ws) + (size_t)BATCH * DIM * NPTS * 4;   // ~164 MB
  bool useT = ws_size >= need_xT;

  k_norm<<<BATCH * NPTS / 4, 256, 0, stream>>>(feat, inv_norm);
  k_init_centers<<<dim3(NSLOT, BATCH), 256, 0, stream>>>(feat, inv_norm, centers,
                                                         cT64, c_sq);
  if (useT)
    k_transpose<<<dim3(NPTS / 64, DIM / 64, BATCH), 256, 0, stream>>>(feat, xT);

  for (int it = 0; it <= NITER; ++it) {
    if (useT)
      k_assign<true><<<dim3(NPTS / 64, BATCH), 256, 0, stream>>>(feat, xT, inv_norm,
                                                                 cT64, c_sq, assign);
    else
      k_assign<false><<<dim3(NPTS / 64, BATCH), 256, 0, stream>>>(feat, xT, inv_norm,
                                                                  cT64, c_sq, assign);
    if (it == NITER) break; // final assignment only
    k_sum<<<dim3(NCHUNK, BATCH), 256, 0, stream>>>(feat, inv_norm, assign, psums, pcnts);
    k_update<<<dim3(NSLOT, BATCH), 256, 0, stream>>>(psums, pcnts, centers, cT64, c_sq);
  }

  k_mask<<<dim3(NPTS / 256, NSLOT, BATCH), 256, 0, stream>>>(assign, out_masks);
  k_copyc<<<dim3(NSLOT, BATCH), 256, 0, stream>>>(centers, out_centers);
}

// Round 5
// 2970.702 us; speedup vs baseline: 2.1975x; 2.1975x over previous
//
#include <hip/hip_runtime.h>
#include <math.h>

// KMeansGrouping: B=32, N=4096, D=256, K=24, 25 iters.
// Round 5: (a) k_sum scratch-spill fix -- 24 NAMED f64 accumulators (round 4's
// acc[24] array was canonicalized to scratch: VGPR_Count=40 < 48 needed),
// counts moved to k_update (exact ints, order-free), loads unrolled x8.
// (b) k_assign scores in f32 (round-2-proven safe on an exact f64 trajectory;
// round 3 failed from f32 STATE, not f32 scoring). Trajectory state & psum
// order bit-identical to the passing rounds 1/2/4.

#define BATCH 32
#define NPTS 4096
#define DIM 256
#define NSLOT 24
#define NITER 25
#define NCHUNK 16
#define PTS 256 // points per k_sum block (round-2/4 psum order)

// ---------------- K0: per-point inverse norm (f64) ----------------
__global__ __launch_bounds__(256) void k_norm(const float* __restrict__ feat,
                                              double* __restrict__ inv_norm) {
  int lane = threadIdx.x & 63;
  int wid = threadIdx.x >> 6;
  int p = blockIdx.x * 4 + wid; // one wave per point
  const float4 v = *(const float4*)(feat + (size_t)p * DIM + lane * 4);
  double s = (double)v.x * v.x + (double)v.y * v.y + (double)v.z * v.z + (double)v.w * v.w;
#pragma unroll
  for (int m = 32; m; m >>= 1) s += __shfl_xor(s, m);
  if (lane == 0) inv_norm[p] = 1.0 / fmax(sqrt(s), 1e-12);
}

__device__ __forceinline__ double block_sum_256(double v, double* red) {
#pragma unroll
  for (int m = 32; m; m >>= 1) v += __shfl_xor(v, m);
  int w = threadIdx.x >> 6;
  if ((threadIdx.x & 63) == 0) red[w] = v;
  __syncthreads();
  return red[0] + red[1] + red[2] + red[3];
}

// ---------------- K0b: initial centers (f64 + f32 [d][k]) + c_sq32 --------
// init_idx = floor(linspace(0, N-1, K)): idx_k = floor(k*4095/23).
__global__ __launch_bounds__(256) void k_init_centers(const float* __restrict__ feat,
                                                      const double* __restrict__ inv_norm,
                                                      double* __restrict__ centers,
                                                      float* __restrict__ cT32,
                                                      float* __restrict__ c_sq32) {
  __shared__ double red[4];
  int t = threadIdx.x, k = blockIdx.x, b = blockIdx.y;
  int idx = (int)((double)k * (NPTS - 1) / (NSLOT - 1));
  double v = (double)feat[((size_t)b * NPTS + idx) * DIM + t] * inv_norm[b * NPTS + idx];
  centers[((size_t)b * NSLOT + k) * DIM + t] = v;
  cT32[((size_t)b * DIM + t) * NSLOT + k] = (float)v;
  double s = block_sum_256(v * v, red);
  if (t == 0) c_sq32[b * NSLOT + k] = (float)s;
}

// ---------------- K0c: tiled transpose feat -> xT[b][d][n] (f32) ----------
__global__ __launch_bounds__(256) void k_transpose(const float* __restrict__ feat,
                                                   float* __restrict__ xT) {
  __shared__ float tile[64][65];
  int ix = threadIdx.x & 63, iy = threadIdx.x >> 6;
  int bx = blockIdx.x, by = blockIdx.y, b = blockIdx.z;
  const float* fb = feat + ((size_t)b * NPTS + bx * 64) * DIM + by * 64;
#pragma unroll
  for (int r = 0; r < 64; r += 4)
    tile[r + iy][ix] = fb[(size_t)(r + iy) * DIM + ix];
  __syncthreads();
  float* xb = xT + ((size_t)b * DIM + by * 64) * NPTS + bx * 64;
#pragma unroll
  for (int r = 0; r < 64; r += 4)
    xb[(size_t)(r + iy) * NPTS + ix] = tile[ix][r + iy];
}

// ---------------- K1: assignment (f32 scoring), quarter-D per wave --------
// Block: 64 points x 4 waves; wave q handles dims [64q, 64q+64). Centers in
// cT32[b][d][k] read wave-uniform -> scalar loads. Waves 1..3 deposit f32
// partial dots in LDS (+1 pad: odd stride, conflict-free); wave 0 combines
// in fixed order, scores, argmins (strict < = first occurrence).
template <bool USE_T>
__global__ __launch_bounds__(256) void k_assign(const float* __restrict__ feat,
                                                const float* __restrict__ xT,
                                                const double* __restrict__ inv_norm,
                                                const float* __restrict__ cT32,
                                                const float* __restrict__ c_sq32,
                                                int* __restrict__ assign) {
  __shared__ float part[3][64][NSLOT + 1]; // 19200 B, odd lane stride
  int lane = threadIdx.x & 63;
  int q = __builtin_amdgcn_readfirstlane(threadIdx.x >> 6);
  int blk = blockIdx.x, b = blockIdx.y;
  int n = blk * 64 + lane;
  const float* cb = cT32 + ((size_t)b * DIM + q * 64) * NSLOT;

  float dot[NSLOT];
#pragma unroll
  for (int k = 0; k < NSLOT; ++k) dot[k] = 0.0f;

  for (int d = 0; d < 64; d += 4) {
    float x0, x1, x2, x3;
    if (USE_T) {
      const float* xp = xT + ((size_t)b * DIM + q * 64 + d) * NPTS + n;
      x0 = xp[0]; x1 = xp[NPTS]; x2 = xp[2 * NPTS]; x3 = xp[3 * NPTS];
    } else {
      float4 v = *(const float4*)(feat + ((size_t)b * NPTS + n) * DIM + q * 64 + d);
      x0 = v.x; x1 = v.y; x2 = v.z; x3 = v.w;
    }
    const float* cp = cb + (size_t)d * NSLOT; // wave-uniform -> s_load
#pragma unroll
    for (int k = 0; k < NSLOT; ++k) {
      float s = dot[k];
      s = fmaf(x0, cp[k], s);
      s = fmaf(x1, cp[NSLOT + k], s);
      s = fmaf(x2, cp[2 * NSLOT + k], s);
      s = fmaf(x3, cp[3 * NSLOT + k], s);
      dot[k] = s;
    }
  }

  if (q) {
#pragma unroll
    for (int k = 0; k < NSLOT; ++k) part[q - 1][lane][k] = dot[k];
  }
  __syncthreads();

  if (q == 0) {
    float inv = (float)inv_norm[b * NPTS + n];
    const float* csq = c_sq32 + b * NSLOT; // uniform -> s_load
    int a = 0;
    float best = 0.0f;
#pragma unroll
    for (int k = 0; k < NSLOT; ++k) {
      float df = dot[k] + part[0][lane][k] + part[1][lane][k] + part[2][lane][k];
      float s = csq[k] - 2.0f * (df * inv);
      if (k == 0) { best = s; }
      else if (s < best) { best = s; a = k; }
    }
    assign[b * NPTS + n] = a;
  }
}

// ---------------- K2: partial center sums (f64, named regs, r2/r4 order) --
#define ACC_DECL(i) double A##i = 0.0;
#define ACC_CASE(i) case i: A##i += x; break;
#define ACC_STORE(i) ps[(size_t)i * DIM] = A##i;
#define FOR24(M) M(0) M(1) M(2) M(3) M(4) M(5) M(6) M(7) M(8) M(9) M(10) M(11) \
                 M(12) M(13) M(14) M(15) M(16) M(17) M(18) M(19) M(20) M(21) M(22) M(23)

__global__ __launch_bounds__(256) void k_sum(const float* __restrict__ feat,
                                             const double* __restrict__ inv_norm,
                                             const int* __restrict__ assign,
                                             double* __restrict__ psums) {
  __shared__ int a_lds[PTS];
  __shared__ double i_lds[PTS];
  int t = threadIdx.x, ch = blockIdx.x, b = blockIdx.y;
  a_lds[t] = assign[b * NPTS + ch * PTS + t];
  i_lds[t] = inv_norm[b * NPTS + ch * PTS + t];
  __syncthreads();

  FOR24(ACC_DECL)

  const float* fb = feat + ((size_t)b * NPTS + ch * PTS) * DIM + t;
  for (int p = 0; p < PTS; p += 8) {
    float xv[8];
#pragma unroll
    for (int j = 0; j < 8; ++j) xv[j] = fb[(size_t)(p + j) * DIM]; // 8 indep loads
#pragma unroll
    for (int j = 0; j < 8; ++j) {
      double x = (double)xv[j] * i_lds[p + j];
      int aa = __builtin_amdgcn_readfirstlane(a_lds[p + j]); // block-uniform
      switch (aa) { FOR24(ACC_CASE) }
    }
  }

  double* ps = psums + ((size_t)(b * NCHUNK + ch) * NSLOT) * DIM + t;
  FOR24(ACC_STORE)
}

// ---------------- K3: reduce partials + exact counts -> new centers -------
__global__ __launch_bounds__(256) void k_update(const double* __restrict__ psums,
                                                const int* __restrict__ assign,
                                                double* __restrict__ centers,
                                                float* __restrict__ cT32,
                                                float* __restrict__ c_sq32) {
  __shared__ double red[4];
  __shared__ int scnt;
  int t = threadIdx.x, k = blockIdx.x, b = blockIdx.y;
  if (t == 0) scnt = 0;
  __syncthreads();

  double s = 0.0; // fixed chunk order, identical to rounds 2/4
#pragma unroll
  for (int ch = 0; ch < NCHUNK; ++ch)
    s += psums[((size_t)(b * NCHUNK + ch) * NSLOT + k) * DIM + t];

  // exact integer counts from assignments (order-free)
  int c_loc = 0;
  const int* ab = assign + b * NPTS;
#pragma unroll
  for (int j = 0; j < NPTS / 256; ++j) c_loc += (ab[t + j * 256] == k) ? 1 : 0;
#pragma unroll
  for (int m = 32; m; m >>= 1) c_loc += __shfl_xor(c_loc, m);
  if ((t & 63) == 0) atomicAdd(&scnt, c_loc);
  __syncthreads();
  int cnt = scnt;

  size_t ci = ((size_t)b * NSLOT + k) * DIM + t;
  double nc = (cnt > 0) ? (s / (double)cnt) : centers[ci];
  centers[ci] = nc;
  cT32[((size_t)b * DIM + t) * NSLOT + k] = (float)nc;
  double sq = block_sum_256(nc * nc, red);
  if (t == 0) c_sq32[b * NSLOT + k] = (float)sq;
}

// ---------------- K4: masks + centers output ----------------
__global__ __launch_bounds__(256) void k_mask(const int* __restrict__ assign,
                                              float* __restrict__ masks) {
  int t = threadIdx.x, nc = blockIdx.x, k = blockIdx.y, b = blockIdx.z;
  int n = nc * 256 + t;
  masks[((size_t)b * NSLOT + k) * NPTS + n] = (assign[b * NPTS + n] == k) ? 1.0f : 0.0f;
}

__global__ __launch_bounds__(256) void k_copyc(const double* __restrict__ centers,
                                               float* __restrict__ out_centers) {
  int t = threadIdx.x, k = blockIdx.x, b = blockIdx.y;
  size_t i = ((size_t)b * NSLOT + k) * DIM + t;
  out_centers[i] = (float)centers[i];
}

extern "C" void kernel_launch(void* const* d_in, const int* in_sizes, int n_in,
                              void* d_out, int out_size, void* d_ws, size_t ws_size,
                              hipStream_t stream) {
  (void)in_sizes; (void)n_in; (void)out_size;
  const float* feat = (const float*)d_in[0];
  float* out_centers = (float*)d_out;                           // (32,24,256)
  float* out_masks = out_centers + (size_t)BATCH * NSLOT * DIM; // (32,24,4096)

  // workspace: ~29 MB fixed + optional 134 MB xT tail.
  char* ws = (char*)d_ws;
  double* inv_norm = (double*)ws; ws += (size_t)BATCH * NPTS * 8;                 // 1.0 MB
  double* centers  = (double*)ws; ws += (size_t)BATCH * NSLOT * DIM * 8;          // 1.5 MB
  float* cT32      = (float*)ws;  ws += (size_t)BATCH * DIM * NSLOT * 4;          // 0.77 MB
  float* c_sq32    = (float*)ws;  ws += (size_t)BATCH * NSLOT * 4;                // 3 KB
  int* assign      = (int*)ws;    ws += (size_t)BATCH * NPTS * 4;                 // 0.5 MB
  double* psums    = (double*)ws; ws += (size_t)BATCH * NCHUNK * NSLOT * DIM * 8; // 25 MB
  float* xT        = (float*)ws;
  size_t need_xT = (size_t)(ws - (char*)d_ws) + (size_t)BATCH * DIM * NPTS * 4;   // ~163 MB
  bool useT = ws_size >= need_xT;

  k_norm<<<BATCH * NPTS / 4, 256, 0, stream>>>(feat, inv_norm);
  k_init_centers<<<dim3(NSLOT, BATCH), 256, 0, stream>>>(feat, inv_norm, centers,
                                                         cT32, c_sq32);
  if (useT)
    k_transpose<<<dim3(NPTS / 64, DIM / 64, BATCH), 256, 0, stream>>>(feat, xT);

  for (int it = 0; it <= NITER; ++it) {
    if (useT)
      k_assign<true><<<dim3(NPTS / 64, BATCH), 256, 0, stream>>>(feat, xT, inv_norm,
                                                                 cT32, c_sq32, assign);
    else
      k_assign<false><<<dim3(NPTS / 64, BATCH), 256, 0, stream>>>(feat, xT, inv_norm,
                                                                  cT32, c_sq32, assign);
    if (it == NITER) break; // final assignment only
    k_sum<<<dim3(NCHUNK, BATCH), 256, 0, stream>>>(feat, inv_norm, assign, psums);
    k_update<<<dim3(NSLOT, BATCH), 256, 0, stream>>>(psums, assign, centers, cT32, c_sq32);
  }

  k_mask<<<dim3(NPTS / 256, NSLOT, BATCH), 256, 0, stream>>>(assign, out_masks);
  k_copyc<<<dim3(NSLOT, BATCH), 256, 0, stream>>>(centers, out_centers);
}

// Round 6
// 1838.134 us; speedup vs baseline: 3.5515x; 1.6162x over previous
//
#include <hip/hip_runtime.h>
#include <math.h>

// KMeansGrouping: B=32, N=4096, D=256, K=24, 25 iters.
// Round 6: fuse k_sum+k_update -> k_cluster (one block per (cluster,batch)).
// Ballot-compacted membership scan: per wave, preload 1024 assigns into 16
// regs, __ballot(a==k) per 64-group, iterate set bits ascending (deterministic)
// -> coalesced float4 row load, 4 f64 FMAs/lane. No psums buffer (-50 MB/iter),
// no switch-branch per point. Wave partials combined in fixed order (f64
// reassociation ~1e-16 vs round 5 -- same class as round 4's passing change).
// k_assign (f32 scoring on exact-f64 state) unchanged from passing round 5.

#define BATCH 32
#define NPTS 4096
#define DIM 256
#define NSLOT 24
#define NITER 25

// ---------------- K0: per-point inverse norm (f64) ----------------
__global__ __launch_bounds__(256) void k_norm(const float* __restrict__ feat,
                                              double* __restrict__ inv_norm) {
  int lane = threadIdx.x & 63;
  int wid = threadIdx.x >> 6;
  int p = blockIdx.x * 4 + wid; // one wave per point
  const float4 v = *(const float4*)(feat + (size_t)p * DIM + lane * 4);
  double s = (double)v.x * v.x + (double)v.y * v.y + (double)v.z * v.z + (double)v.w * v.w;
#pragma unroll
  for (int m = 32; m; m >>= 1) s += __shfl_xor(s, m);
  if (lane == 0) inv_norm[p] = 1.0 / fmax(sqrt(s), 1e-12);
}

__device__ __forceinline__ double block_sum_256(double v, double* red) {
#pragma unroll
  for (int m = 32; m; m >>= 1) v += __shfl_xor(v, m);
  int w = threadIdx.x >> 6;
  if ((threadIdx.x & 63) == 0) red[w] = v;
  __syncthreads();
  return red[0] + red[1] + red[2] + red[3];
}

// ---------------- K0b: initial centers (f64 + f32 [d][k]) + c_sq32 --------
// init_idx = floor(linspace(0, N-1, K)): idx_k = floor(k*4095/23).
__global__ __launch_bounds__(256) void k_init_centers(const float* __restrict__ feat,
                                                      const double* __restrict__ inv_norm,
                                                      double* __restrict__ centers,
                                                      float* __restrict__ cT32,
                                                      float* __restrict__ c_sq32) {
  __shared__ double red[4];
  int t = threadIdx.x, k = blockIdx.x, b = blockIdx.y;
  int idx = (int)((double)k * (NPTS - 1) / (NSLOT - 1));
  double v = (double)feat[((size_t)b * NPTS + idx) * DIM + t] * inv_norm[b * NPTS + idx];
  centers[((size_t)b * NSLOT + k) * DIM + t] = v;
  cT32[((size_t)b * DIM + t) * NSLOT + k] = (float)v;
  double s = block_sum_256(v * v, red);
  if (t == 0) c_sq32[b * NSLOT + k] = (float)s;
}

// ---------------- K0c: tiled transpose feat -> xT[b][d][n] (f32) ----------
__global__ __launch_bounds__(256) void k_transpose(const float* __restrict__ feat,
                                                   float* __restrict__ xT) {
  __shared__ float tile[64][65];
  int ix = threadIdx.x & 63, iy = threadIdx.x >> 6;
  int bx = blockIdx.x, by = blockIdx.y, b = blockIdx.z;
  const float* fb = feat + ((size_t)b * NPTS + bx * 64) * DIM + by * 64;
#pragma unroll
  for (int r = 0; r < 64; r += 4)
    tile[r + iy][ix] = fb[(size_t)(r + iy) * DIM + ix];
  __syncthreads();
  float* xb = xT + ((size_t)b * DIM + by * 64) * NPTS + bx * 64;
#pragma unroll
  for (int r = 0; r < 64; r += 4)
    xb[(size_t)(r + iy) * NPTS + ix] = tile[ix][r + iy];
}

// ---------------- K1: assignment (f32 scoring), quarter-D per wave --------
template <bool USE_T>
__global__ __launch_bounds__(256) void k_assign(const float* __restrict__ feat,
                                                const float* __restrict__ xT,
                                                const double* __restrict__ inv_norm,
                                                const float* __restrict__ cT32,
                                                const float* __restrict__ c_sq32,
                                                int* __restrict__ assign) {
  __shared__ float part[3][64][NSLOT + 1]; // 19200 B, odd lane stride
  int lane = threadIdx.x & 63;
  int q = __builtin_amdgcn_readfirstlane(threadIdx.x >> 6);
  int blk = blockIdx.x, b = blockIdx.y;
  int n = blk * 64 + lane;
  const float* cb = cT32 + ((size_t)b * DIM + q * 64) * NSLOT;

  float dot[NSLOT];
#pragma unroll
  for (int k = 0; k < NSLOT; ++k) dot[k] = 0.0f;

  for (int d = 0; d < 64; d += 4) {
    float x0, x1, x2, x3;
    if (USE_T) {
      const float* xp = xT + ((size_t)b * DIM + q * 64 + d) * NPTS + n;
      x0 = xp[0]; x1 = xp[NPTS]; x2 = xp[2 * NPTS]; x3 = xp[3 * NPTS];
    } else {
      float4 v = *(const float4*)(feat + ((size_t)b * NPTS + n) * DIM + q * 64 + d);
      x0 = v.x; x1 = v.y; x2 = v.z; x3 = v.w;
    }
    const float* cp = cb + (size_t)d * NSLOT; // wave-uniform -> s_load
#pragma unroll
    for (int k = 0; k < NSLOT; ++k) {
      float s = dot[k];
      s = fmaf(x0, cp[k], s);
      s = fmaf(x1, cp[NSLOT + k], s);
      s = fmaf(x2, cp[2 * NSLOT + k], s);
      s = fmaf(x3, cp[3 * NSLOT + k], s);
      dot[k] = s;
    }
  }

  if (q) {
#pragma unroll
    for (int k = 0; k < NSLOT; ++k) part[q - 1][lane][k] = dot[k];
  }
  __syncthreads();

  if (q == 0) {
    float inv = (float)inv_norm[b * NPTS + n];
    const float* csq = c_sq32 + b * NSLOT; // uniform -> s_load
    int a = 0;
    float best = 0.0f;
#pragma unroll
    for (int k = 0; k < NSLOT; ++k) {
      float df = dot[k] + part[0][lane][k] + part[1][lane][k] + part[2][lane][k];
      float s = csq[k] - 2.0f * (df * inv);
      if (k == 0) { best = s; }
      else if (s < best) { best = s; a = k; }
    }
    assign[b * NPTS + n] = a;
  }
}

// ---------------- K2: fused cluster sum + center update ----------------
// Block (k, b): wave w owns points [w*1024, w*1024+1024). Ballot-compacted
// scan; matching rows loaded coalesced (lane = 4 dims via float4); f64
// accumulate in ascending-p order; wave partials combined in fixed order.
__global__ __launch_bounds__(256) void k_cluster(const float* __restrict__ feat,
                                                 const double* __restrict__ inv_norm,
                                                 const int* __restrict__ assign,
                                                 double* __restrict__ centers,
                                                 float* __restrict__ cT32,
                                                 float* __restrict__ c_sq32) {
  __shared__ double part[4][DIM]; // 8 KB
  __shared__ double red[4];
  __shared__ int wcnt[4];
  int k = blockIdx.x, b = blockIdx.y;
  int lane = threadIdx.x & 63;
  int w = __builtin_amdgcn_readfirstlane(threadIdx.x >> 6);

  // preload this wave's 1024 assigns into 16 regs (coalesced)
  const int* ab = assign + b * NPTS + w * 1024;
  int av[16];
#pragma unroll
  for (int j = 0; j < 16; ++j) av[j] = ab[lane + j * 64];

  const float* fb = feat + (size_t)b * NPTS * DIM + lane * 4;
  const double* ib = inv_norm + b * NPTS;

  double a0 = 0.0, a1 = 0.0, a2 = 0.0, a3 = 0.0;
  int cnt = 0;
#pragma unroll
  for (int j = 0; j < 16; ++j) {
    unsigned long long m = __ballot(av[j] == k);
    cnt += __popcll(m);
    while (m) {
      int bit = __ffsll((long long)m) - 1;
      m &= m - 1;
      int p = __builtin_amdgcn_readfirstlane(w * 1024 + j * 64 + bit);
      double inv = ib[p]; // uniform -> scalar load
      float4 v = *(const float4*)(fb + (size_t)p * DIM);
      a0 += (double)v.x * inv;
      a1 += (double)v.y * inv;
      a2 += (double)v.z * inv;
      a3 += (double)v.w * inv;
    }
  }

  part[w][lane * 4 + 0] = a0;
  part[w][lane * 4 + 1] = a1;
  part[w][lane * 4 + 2] = a2;
  part[w][lane * 4 + 3] = a3;
  if (lane == 0) wcnt[w] = cnt; // ballot/popc -> lane-uniform
  __syncthreads();

  int t = threadIdx.x; // dim
  double s = ((part[0][t] + part[1][t]) + part[2][t]) + part[3][t]; // fixed order
  int total = wcnt[0] + wcnt[1] + wcnt[2] + wcnt[3];

  size_t ci = ((size_t)b * NSLOT + k) * DIM + t;
  double nc = (total > 0) ? (s / (double)total) : centers[ci];
  centers[ci] = nc;
  cT32[((size_t)b * DIM + t) * NSLOT + k] = (float)nc;
  double sq = block_sum_256(nc * nc, red);
  if (t == 0) c_sq32[b * NSLOT + k] = (float)sq;
}

// ---------------- K4: masks + centers output ----------------
__global__ __launch_bounds__(256) void k_mask(const int* __restrict__ assign,
                                              float* __restrict__ masks) {
  int t = threadIdx.x, nc = blockIdx.x, k = blockIdx.y, b = blockIdx.z;
  int n = nc * 256 + t;
  masks[((size_t)b * NSLOT + k) * NPTS + n] = (assign[b * NPTS + n] == k) ? 1.0f : 0.0f;
}

__global__ __launch_bounds__(256) void k_copyc(const double* __restrict__ centers,
                                               float* __restrict__ out_centers) {
  int t = threadIdx.x, k = blockIdx.x, b = blockIdx.y;
  size_t i = ((size_t)b * NSLOT + k) * DIM + t;
  out_centers[i] = (float)centers[i];
}

extern "C" void kernel_launch(void* const* d_in, const int* in_sizes, int n_in,
                              void* d_out, int out_size, void* d_ws, size_t ws_size,
                              hipStream_t stream) {
  (void)in_sizes; (void)n_in; (void)out_size;
  const float* feat = (const float*)d_in[0];
  float* out_centers = (float*)d_out;                           // (32,24,256)
  float* out_masks = out_centers + (size_t)BATCH * NSLOT * DIM; // (32,24,4096)

  // workspace: ~4 MB fixed + optional 134 MB xT tail.
  char* ws = (char*)d_ws;
  double* inv_norm = (double*)ws; ws += (size_t)BATCH * NPTS * 8;        // 1.0 MB
  double* centers  = (double*)ws; ws += (size_t)BATCH * NSLOT * DIM * 8; // 1.5 MB
  float* cT32      = (float*)ws;  ws += (size_t)BATCH * DIM * NSLOT * 4; // 0.77 MB
  float* c_sq32    = (float*)ws;  ws += (size_t)BATCH * NSLOT * 4;       // 3 KB
  int* assign      = (int*)ws;    ws += (size_t)BATCH * NPTS * 4;        // 0.5 MB
  float* xT        = (float*)ws;
  size_t need_xT = (size_t)(ws - (char*)d_ws) + (size_t)BATCH * DIM * NPTS * 4; // ~138 MB
  bool useT = ws_size >= need_xT;

  k_norm<<<BATCH * NPTS / 4, 256, 0, stream>>>(feat, inv_norm);
  k_init_centers<<<dim3(NSLOT, BATCH), 256, 0, stream>>>(feat, inv_norm, centers,
                                                         cT32, c_sq32);
  if (useT)
    k_transpose<<<dim3(NPTS / 64, DIM / 64, BATCH), 256, 0, stream>>>(feat, xT);

  for (int it = 0; it <= NITER; ++it) {
    if (useT)
      k_assign<true><<<dim3(NPTS / 64, BATCH), 256, 0, stream>>>(feat, xT, inv_norm,
                                                                 cT32, c_sq32, assign);
    else
      k_assign<false><<<dim3(NPTS / 64, BATCH), 256, 0, stream>>>(feat, xT, inv_norm,
                                                                  cT32, c_sq32, assign);
    if (it == NITER) break; // final assignment only
    k_cluster<<<dim3(NSLOT, BATCH), 256, 0, stream>>>(feat, inv_norm, assign,
                                                      centers, cT32, c_sq32);
  }

  k_mask<<<dim3(NPTS / 256, NSLOT, BATCH), 256, 0, stream>>>(assign, out_masks);
  k_copyc<<<dim3(NSLOT, BATCH), 256, 0, stream>>>(centers, out_centers);
}